// Round 1
// baseline (277.440 us; speedup 1.0000x reference)
//
#include <hip/hip_runtime.h>

#define N_NODES 384
#define CCH 256        // channels
#define HT 60          // height
#define CH (CCH*HT)    // 15360 floats per node slab
#define CH4 (CH/4)     // 3840 float4
#define LN_EPS 1e-5f

// ---- prep: transpose/split W_conv into Wt1[c][o] = W1-W2, Wt2[c][o] = W2 ----
__global__ void k_prep_w(const float* __restrict__ Wc, float* __restrict__ Wt1,
                         float* __restrict__ Wt2) {
    int idx = blockIdx.x * 256 + threadIdx.x;      // 65536
    int o = idx & 255, c = idx >> 8;
    float w1 = Wc[o * 768 + c];
    float w2 = Wc[o * 768 + 256 + c];
    Wt1[c * 256 + o] = w1 - w2;
    Wt2[c * 256 + o] = w2;
}

// ---- prep: M[j][o] = sum_k W_edge[j,k]*W3[o,k]; bias0[o] = sum_k b_edge[k]*W3[o,k]
__global__ void k_prep_m(const float* __restrict__ Wc, const float* __restrict__ We,
                         const float* __restrict__ be, float* __restrict__ M,
                         float* __restrict__ bias0) {
    int o = threadIdx.x;
    float m0=0,m1=0,m2=0,m3=0,m4=0,bb=0;
    for (int k = 0; k < 256; ++k) {
        float w3 = Wc[o * 768 + 512 + k];
        m0 += We[0*256+k] * w3;
        m1 += We[1*256+k] * w3;
        m2 += We[2*256+k] * w3;
        m3 += We[3*256+k] * w3;
        m4 += We[4*256+k] * w3;
        bb += be[k] * w3;
    }
    M[0*256+o]=m0; M[1*256+o]=m1; M[2*256+o]=m2; M[3*256+o]=m3; M[4*256+o]=m4;
    bias0[o] = bb;
}

// ---- per-edge coefficient c[e][o] = bias0[o] + sum_j ea[e,j]*M[j,o] ----
__global__ void k_edge_c(const float* __restrict__ ea, const float* __restrict__ M,
                         const float* __restrict__ bias0, float* __restrict__ cbuf) {
    int e = blockIdx.x, o = threadIdx.x;
    float s = bias0[o];
#pragma unroll
    for (int j = 0; j < 5; ++j) s += ea[e * 5 + j] * M[j * 256 + o];
    cbuf[e * 256 + o] = s;
}

// ---- CSR build (dst-indexed), deterministic after per-node sort ----
__global__ void k_count(const int* __restrict__ dst, int E, int* counts) {
    int e = blockIdx.x * 256 + threadIdx.x;
    if (e < E) atomicAdd(&counts[dst[e]], 1);
}
__global__ void k_scan(const int* __restrict__ counts, int* __restrict__ offsets) {
    __shared__ int sc[512];
    int tid = threadIdx.x;
    int v = (tid < N_NODES) ? counts[tid] : 0;
    sc[tid] = v; __syncthreads();
    for (int d = 1; d < 512; d <<= 1) {
        int t = (tid >= d) ? sc[tid - d] : 0;
        __syncthreads();
        sc[tid] += t; __syncthreads();
    }
    if (tid < N_NODES) offsets[tid + 1] = sc[tid];
    if (tid == 0) offsets[0] = 0;
}
__global__ void k_fill(const int* __restrict__ dst, int E, const int* __restrict__ offsets,
                       int* cursor, int* __restrict__ elist) {
    int e = blockIdx.x * 256 + threadIdx.x;
    if (e < E) {
        int d = dst[e];
        int slot = offsets[d] + atomicAdd(&cursor[d], 1);
        elist[slot] = e;
    }
}
__global__ void k_sort(const int* __restrict__ offsets, int* __restrict__ elist) {
    int n = blockIdx.x * blockDim.x + threadIdx.x;
    if (n >= N_NODES) return;
    int lo = offsets[n], hi = offsets[n + 1];
    for (int i = lo + 1; i < hi; ++i) {
        int key = elist[i]; int j = i - 1;
        while (j >= lo && elist[j] > key) { elist[j + 1] = elist[j]; --j; }
        elist[j + 1] = key;
    }
}

// ---- per-node GEMM: A[n]=(W1-W2)@x[n], B[n]=W2@x[n]  (256x256 @ 256x60, x in LDS)
__global__ __launch_bounds__(256) void k_node_ab(const float* __restrict__ x,
                                                 const float* __restrict__ Wt1,
                                                 const float* __restrict__ Wt2,
                                                 float* __restrict__ A,
                                                 float* __restrict__ B) {
    __shared__ float xl[CH];
    int n = blockIdx.x, tid = threadIdx.x;
    const float4* xg = (const float4*)(x + (size_t)n * CH);
    float4* xl4 = (float4*)xl;
    for (int i = tid; i < CH4; i += 256) xl4[i] = xg[i];
    __syncthreads();
    int o = tid;
    float4 a[15], b[15];
#pragma unroll
    for (int r = 0; r < 15; ++r) {
        a[r] = make_float4(0.f, 0.f, 0.f, 0.f);
        b[r] = make_float4(0.f, 0.f, 0.f, 0.f);
    }
    for (int c = 0; c < 256; ++c) {
        float w1 = Wt1[c * 256 + o];
        float w2 = Wt2[c * 256 + o];
        const float4* xr = (const float4*)(xl + c * HT);
#pragma unroll
        for (int r = 0; r < 15; ++r) {
            float4 xv = xr[r];
            a[r].x += w1 * xv.x; a[r].y += w1 * xv.y; a[r].z += w1 * xv.z; a[r].w += w1 * xv.w;
            b[r].x += w2 * xv.x; b[r].y += w2 * xv.y; b[r].z += w2 * xv.z; b[r].w += w2 * xv.w;
        }
    }
    float4* Ao = (float4*)(A + (size_t)n * CH);
    float4* Bo = (float4*)(B + (size_t)n * CH);
#pragma unroll
    for (int r = 0; r < 15; ++r) {
        Ao[o * 15 + r] = a[r];
        Bo[o * 15 + r] = b[r];
    }
}

// ---- fused per-node: for each incoming edge, m=A[n]+B[src]+c_e, LN, ReLU, accumulate
__global__ __launch_bounds__(256) void k_agg(const float* __restrict__ A,
                                             const float* __restrict__ B,
                                             const float* __restrict__ cbuf,
                                             const int* __restrict__ srcArr,
                                             const int* __restrict__ offsets,
                                             const int* __restrict__ elist,
                                             const float* __restrict__ gamma,
                                             const float* __restrict__ beta,
                                             float* __restrict__ out) {
    __shared__ float cl[256];
    __shared__ float red[8];
    int n = blockIdx.x, tid = threadIdx.x;
    int lane = tid & 63, wv = tid >> 6;

    float4 aA[15], acc[15];
    const float4* Ab = (const float4*)(A + (size_t)n * CH);
#pragma unroll
    for (int r = 0; r < 15; ++r) {
        aA[r] = Ab[tid + 256 * r];
        acc[r] = make_float4(0.f, 0.f, 0.f, 0.f);
    }
    int lo = offsets[n], hi = offsets[n + 1];
    const float4* g4 = (const float4*)gamma;
    const float4* b4 = (const float4*)beta;

    for (int k = lo; k < hi; ++k) {
        int e = elist[k];
        int s = srcArr[e];
        __syncthreads();
        cl[tid] = cbuf[(size_t)e * 256 + tid];
        __syncthreads();
        const float4* Bb = (const float4*)(B + (size_t)s * CH);
        float4 m[15];
        float s1 = 0.f, s2 = 0.f;
#pragma unroll
        for (int r = 0; r < 15; ++r) {
            float4 bv = Bb[tid + 256 * r];
            int oc = (tid + 256 * r) / 15;       // channel of this float4
            float cc = cl[oc];
            float4 mv;
            mv.x = aA[r].x + bv.x + cc;
            mv.y = aA[r].y + bv.y + cc;
            mv.z = aA[r].z + bv.z + cc;
            mv.w = aA[r].w + bv.w + cc;
            m[r] = mv;
            s1 += mv.x + mv.y + mv.z + mv.w;
            s2 += mv.x * mv.x + mv.y * mv.y + mv.z * mv.z + mv.w * mv.w;
        }
#pragma unroll
        for (int off2 = 32; off2 >= 1; off2 >>= 1) {
            s1 += __shfl_xor(s1, off2, 64);
            s2 += __shfl_xor(s2, off2, 64);
        }
        if (lane == 0) { red[wv * 2] = s1; red[wv * 2 + 1] = s2; }
        __syncthreads();
        float S1 = red[0] + red[2] + red[4] + red[6];
        float S2 = red[1] + red[3] + red[5] + red[7];
        float mu = S1 * (1.0f / (float)CH);
        float var = S2 * (1.0f / (float)CH) - mu * mu;
        float rstd = rsqrtf(var + LN_EPS);
#pragma unroll
        for (int r = 0; r < 15; ++r) {
            float4 gv = g4[tid + 256 * r];
            float4 bv = b4[tid + 256 * r];
            float4 mv = m[r];
            float vx = (mv.x - mu) * rstd * gv.x + bv.x; vx = fmaxf(vx, 0.f);
            float vy = (mv.y - mu) * rstd * gv.y + bv.y; vy = fmaxf(vy, 0.f);
            float vz = (mv.z - mu) * rstd * gv.z + bv.z; vz = fmaxf(vz, 0.f);
            float vw = (mv.w - mu) * rstd * gv.w + bv.w; vw = fmaxf(vw, 0.f);
            acc[r].x += vx; acc[r].y += vy; acc[r].z += vz; acc[r].w += vw;
        }
    }
    float4* ob = (float4*)(out + (size_t)n * CH);
#pragma unroll
    for (int r = 0; r < 15; ++r) ob[tid + 256 * r] = acc[r];
}

extern "C" void kernel_launch(void* const* d_in, const int* in_sizes, int n_in,
                              void* d_out, int out_size, void* d_ws, size_t ws_size,
                              hipStream_t stream) {
    const float* x     = (const float*)d_in[0];
    const float* ea    = (const float*)d_in[1];
    const int*   ei    = (const int*)d_in[2];
    const float* We    = (const float*)d_in[3];
    const float* be    = (const float*)d_in[4];
    const float* Wc    = (const float*)d_in[5];
    const float* gamma = (const float*)d_in[6];
    const float* beta  = (const float*)d_in[7];
    const int E = in_sizes[2] / 2;
    const int* src = ei;
    const int* dst = ei + E;

    char* ws = (char*)d_ws;
    size_t off = 0;
    auto alloc = [&](size_t bytes) -> void* {
        void* p = ws + off;
        off += (bytes + 255) & ~(size_t)255;
        return p;
    };
    float* A      = (float*)alloc((size_t)N_NODES * CH * 4);
    float* Bm     = (float*)alloc((size_t)N_NODES * CH * 4);
    float* cbuf   = (float*)alloc((size_t)E * 256 * 4);
    float* Wt1    = (float*)alloc(256 * 256 * 4);
    float* Wt2    = (float*)alloc(256 * 256 * 4);
    float* M      = (float*)alloc(5 * 256 * 4);
    float* bias0  = (float*)alloc(256 * 4);
    int*   counts = (int*)alloc(N_NODES * 4);
    int*   cursor = (int*)alloc(N_NODES * 4);
    int*   offs   = (int*)alloc((N_NODES + 1) * 4);
    int*   elist  = (int*)alloc((size_t)E * 4);

    hipMemsetAsync(counts, 0, N_NODES * 4, stream);
    hipMemsetAsync(cursor, 0, N_NODES * 4, stream);

    k_prep_w<<<256, 256, 0, stream>>>(Wc, Wt1, Wt2);
    k_prep_m<<<1, 256, 0, stream>>>(Wc, We, be, M, bias0);
    k_edge_c<<<E, 256, 0, stream>>>(ea, M, bias0, cbuf);
    k_count<<<(E + 255) / 256, 256, 0, stream>>>(dst, E, counts);
    k_scan<<<1, 512, 0, stream>>>(counts, offs);
    k_fill<<<(E + 255) / 256, 256, 0, stream>>>(dst, E, offs, cursor, elist);
    k_sort<<<2, 192, 0, stream>>>(offs, elist);
    k_node_ab<<<N_NODES, 256, 0, stream>>>(x, Wt1, Wt2, A, Bm);
    k_agg<<<N_NODES, 256, 0, stream>>>(A, Bm, cbuf, src, offs, elist, gamma, beta, (float*)d_out);
}

// Round 2
// 193.258 us; speedup vs baseline: 1.4356x; 1.4356x over previous
//
#include <hip/hip_runtime.h>

#define N_NODES 384
#define CCH 256        // channels
#define HT 60          // height
#define CH (CCH*HT)    // 15360 floats per node slab
#define CH4 (CH/4)     // 3840 float4
#define LN_EPS 1e-5f

typedef __attribute__((ext_vector_type(8))) short bf16x8;
typedef __attribute__((ext_vector_type(4))) float f32x4;

__device__ inline unsigned short f2bf(float f) {
    unsigned int u = __float_as_uint(f);
    unsigned int r = (u + 0x7FFF + ((u >> 16) & 1)) >> 16;   // RNE
    return (unsigned short)r;
}

// ---- prep: W_conv -> MFMA A-fragment-linear bf16 buffer.
// Logical A matrix: 512x256, rows 0..255 = W1-W2, rows 256..511 = W2.
// Fragment element (mt, ks, lane, j) -> A[o = mt*16 + (lane&15)][c = ks*32 + (lane>>4)*8 + j]
// stored at Wfrag[((mt*8 + ks)*64 + lane)*8 + j].
__global__ void k_prep_wfrag(const float* __restrict__ Wc, unsigned short* __restrict__ Wfrag) {
    int idx = blockIdx.x * 256 + threadIdx.x;      // 131072 total
    int j = idx & 7, lane = (idx >> 3) & 63, ks = (idx >> 9) & 7, mt = idx >> 12;
    int o = mt * 16 + (lane & 15);
    int c = ks * 32 + (lane >> 4) * 8 + j;
    float v;
    if (o < 256) v = Wc[o * 768 + c] - Wc[o * 768 + 256 + c];   // W1 - W2
    else         v = Wc[(o - 256) * 768 + 256 + c];             // W2
    Wfrag[idx] = f2bf(v);
}

// ---- prep: M[j][o] = sum_k W_edge[j,k]*W3[o,k]; bias0[o] = sum_k b_edge[k]*W3[o,k]
__global__ void k_prep_m(const float* __restrict__ Wc, const float* __restrict__ We,
                         const float* __restrict__ be, float* __restrict__ M,
                         float* __restrict__ bias0) {
    int o = threadIdx.x;
    float m0=0,m1=0,m2=0,m3=0,m4=0,bb=0;
    for (int k = 0; k < 256; ++k) {
        float w3 = Wc[o * 768 + 512 + k];
        m0 += We[0*256+k] * w3;
        m1 += We[1*256+k] * w3;
        m2 += We[2*256+k] * w3;
        m3 += We[3*256+k] * w3;
        m4 += We[4*256+k] * w3;
        bb += be[k] * w3;
    }
    M[0*256+o]=m0; M[1*256+o]=m1; M[2*256+o]=m2; M[3*256+o]=m3; M[4*256+o]=m4;
    bias0[o] = bb;
}

// ---- per-edge coefficient c[e][o] = bias0[o] + sum_j ea[e,j]*M[j,o] ----
__global__ void k_edge_c(const float* __restrict__ ea, const float* __restrict__ M,
                         const float* __restrict__ bias0, float* __restrict__ cbuf) {
    int e = blockIdx.x, o = threadIdx.x;
    float s = bias0[o];
#pragma unroll
    for (int j = 0; j < 5; ++j) s += ea[e * 5 + j] * M[j * 256 + o];
    cbuf[e * 256 + o] = s;
}

// ---- CSR build (dst-indexed), deterministic after per-node sort ----
__global__ void k_count(const int* __restrict__ dst, int E, int* counts) {
    int e = blockIdx.x * 256 + threadIdx.x;
    if (e < E) atomicAdd(&counts[dst[e]], 1);
}
__global__ void k_scan(const int* __restrict__ counts, int* __restrict__ offsets) {
    __shared__ int sc[512];
    int tid = threadIdx.x;
    int v = (tid < N_NODES) ? counts[tid] : 0;
    sc[tid] = v; __syncthreads();
    for (int d = 1; d < 512; d <<= 1) {
        int t = (tid >= d) ? sc[tid - d] : 0;
        __syncthreads();
        sc[tid] += t; __syncthreads();
    }
    if (tid < N_NODES) offsets[tid + 1] = sc[tid];
    if (tid == 0) offsets[0] = 0;
}
__global__ void k_fill(const int* __restrict__ dst, int E, const int* __restrict__ offsets,
                       int* cursor, int* __restrict__ elist) {
    int e = blockIdx.x * 256 + threadIdx.x;
    if (e < E) {
        int d = dst[e];
        int slot = offsets[d] + atomicAdd(&cursor[d], 1);
        elist[slot] = e;
    }
}
__global__ void k_sort(const int* __restrict__ offsets, int* __restrict__ elist) {
    int n = blockIdx.x * blockDim.x + threadIdx.x;
    if (n >= N_NODES) return;
    int lo = offsets[n], hi = offsets[n + 1];
    for (int i = lo + 1; i < hi; ++i) {
        int key = elist[i]; int j = i - 1;
        while (j >= lo && elist[j] > key) { elist[j + 1] = elist[j]; --j; }
        elist[j + 1] = key;
    }
}

// ---- per-node GEMM via MFMA: [A;B](512x60) = Wstacked(512x256) @ x[n](256x60)
// x staged transposed in LDS as bf16 [h=64][c=256], XOR-swizzled (granule=8 ushorts).
// 4 waves; wave w owns m-tiles w*8..w*8+7 (16 rows each), all 4 n-tiles, K=256 in 8 steps.
__global__ __launch_bounds__(256) void k_node_mfma(const float* __restrict__ x,
                                                   const unsigned short* __restrict__ Wfrag,
                                                   float* __restrict__ A,
                                                   float* __restrict__ B) {
    __shared__ unsigned short xT[64 * 256];   // 32 KiB, [h][c] bf16, swizzled
    int n = blockIdx.x, tid = threadIdx.x;

    // zero pad rows h=60..63 (avoid 0xAA garbage feeding MFMA)
    for (int i = tid; i < 4 * 256; i += 256) {
        int h = 60 + (i >> 8), c = i & 255;
        xT[h * 256 + (c ^ ((h & 7) << 3))] = 0;
    }
    // stage x[n] (fp32, (c,h) row-major) -> xT (bf16, (h,c)), coalesced float4 reads
    const float4* xg = (const float4*)(x + (size_t)n * CH);
    for (int i = tid; i < CH4; i += 256) {
        int c = i / 15;
        int h0 = (i - c * 15) * 4;
        float4 v = xg[i];
        xT[(h0+0) * 256 + (c ^ (((h0+0) & 7) << 3))] = f2bf(v.x);
        xT[(h0+1) * 256 + (c ^ (((h0+1) & 7) << 3))] = f2bf(v.y);
        xT[(h0+2) * 256 + (c ^ (((h0+2) & 7) << 3))] = f2bf(v.z);
        xT[(h0+3) * 256 + (c ^ (((h0+3) & 7) << 3))] = f2bf(v.w);
    }
    __syncthreads();

    int w = tid >> 6, lane = tid & 63;
    int l15 = lane & 15, lg = lane >> 4;

    f32x4 acc[8][4];
#pragma unroll
    for (int mt = 0; mt < 8; ++mt)
#pragma unroll
        for (int nt = 0; nt < 4; ++nt)
            acc[mt][nt] = (f32x4){0.f, 0.f, 0.f, 0.f};

    const unsigned short* wbase = Wfrag + ((size_t)(w * 8) * 8 + 0) * 64 * 8;
    for (int ks = 0; ks < 8; ++ks) {
        // B-fragments: B[k = ks*32 + lg*8 + j][col = nt*16 + l15] from xT
        bf16x8 bfr[4];
#pragma unroll
        for (int nt = 0; nt < 4; ++nt) {
            int row = nt * 16 + l15;
            int col = ks * 32 + lg * 8;
            int idx = row * 256 + (col ^ ((row & 7) << 3));
            bfr[nt] = *(const bf16x8*)(&xT[idx]);
        }
#pragma unroll
        for (int mt = 0; mt < 8; ++mt) {
            const bf16x8 afr = *(const bf16x8*)(wbase + (((size_t)mt * 8 + ks) * 64 + lane) * 8);
#pragma unroll
            for (int nt = 0; nt < 4; ++nt)
                acc[mt][nt] = __builtin_amdgcn_mfma_f32_16x16x32_bf16(afr, bfr[nt], acc[mt][nt], 0, 0, 0);
        }
    }

    // epilogue: D[o = mtg*16 + 4*lg + r][h = nt*16 + l15]
#pragma unroll
    for (int mt = 0; mt < 8; ++mt) {
        int mtg = w * 8 + mt;
        int obase = mtg * 16 + 4 * lg;
        float* dst0 = (obase < 256) ? (A + (size_t)n * CH + obase * 60)
                                    : (B + (size_t)n * CH + (size_t)(obase - 256) * 60);
#pragma unroll
        for (int nt = 0; nt < 4; ++nt) {
            int h = nt * 16 + l15;
            if (h < 60) {
#pragma unroll
                for (int r = 0; r < 4; ++r)
                    dst0[r * 60 + h] = acc[mt][nt][r];
            }
        }
    }
}

// ---- fused per-node: for each incoming edge, m=A[n]+B[src]+c_e, LN, ReLU, accumulate
__global__ __launch_bounds__(256) void k_agg(const float* __restrict__ A,
                                             const float* __restrict__ B,
                                             const float* __restrict__ cbuf,
                                             const int* __restrict__ srcArr,
                                             const int* __restrict__ offsets,
                                             const int* __restrict__ elist,
                                             const float* __restrict__ gamma,
                                             const float* __restrict__ beta,
                                             float* __restrict__ out) {
    __shared__ float cl[256];
    __shared__ float red[8];
    int n = blockIdx.x, tid = threadIdx.x;
    int lane = tid & 63, wv = tid >> 6;

    float4 aA[15], acc[15];
    const float4* Ab = (const float4*)(A + (size_t)n * CH);
#pragma unroll
    for (int r = 0; r < 15; ++r) {
        aA[r] = Ab[tid + 256 * r];
        acc[r] = make_float4(0.f, 0.f, 0.f, 0.f);
    }
    int lo = offsets[n], hi = offsets[n + 1];
    const float4* g4 = (const float4*)gamma;
    const float4* b4 = (const float4*)beta;

    for (int k = lo; k < hi; ++k) {
        int e = elist[k];
        int s = srcArr[e];
        __syncthreads();
        cl[tid] = cbuf[(size_t)e * 256 + tid];
        __syncthreads();
        const float4* Bb = (const float4*)(B + (size_t)s * CH);
        float4 m[15];
        float s1 = 0.f, s2 = 0.f;
#pragma unroll
        for (int r = 0; r < 15; ++r) {
            float4 bv = Bb[tid + 256 * r];
            int oc = (tid + 256 * r) / 15;       // channel of this float4
            float cc = cl[oc];
            float4 mv;
            mv.x = aA[r].x + bv.x + cc;
            mv.y = aA[r].y + bv.y + cc;
            mv.z = aA[r].z + bv.z + cc;
            mv.w = aA[r].w + bv.w + cc;
            m[r] = mv;
            s1 += mv.x + mv.y + mv.z + mv.w;
            s2 += mv.x * mv.x + mv.y * mv.y + mv.z * mv.z + mv.w * mv.w;
        }
#pragma unroll
        for (int off2 = 32; off2 >= 1; off2 >>= 1) {
            s1 += __shfl_xor(s1, off2, 64);
            s2 += __shfl_xor(s2, off2, 64);
        }
        if (lane == 0) { red[wv * 2] = s1; red[wv * 2 + 1] = s2; }
        __syncthreads();
        float S1 = red[0] + red[2] + red[4] + red[6];
        float S2 = red[1] + red[3] + red[5] + red[7];
        float mu = S1 * (1.0f / (float)CH);
        float var = S2 * (1.0f / (float)CH) - mu * mu;
        float rstd = rsqrtf(var + LN_EPS);
#pragma unroll
        for (int r = 0; r < 15; ++r) {
            float4 gv = g4[tid + 256 * r];
            float4 bv = b4[tid + 256 * r];
            float4 mv = m[r];
            float vx = (mv.x - mu) * rstd * gv.x + bv.x; vx = fmaxf(vx, 0.f);
            float vy = (mv.y - mu) * rstd * gv.y + bv.y; vy = fmaxf(vy, 0.f);
            float vz = (mv.z - mu) * rstd * gv.z + bv.z; vz = fmaxf(vz, 0.f);
            float vw = (mv.w - mu) * rstd * gv.w + bv.w; vw = fmaxf(vw, 0.f);
            acc[r].x += vx; acc[r].y += vy; acc[r].z += vz; acc[r].w += vw;
        }
    }
    float4* ob = (float4*)(out + (size_t)n * CH);
#pragma unroll
    for (int r = 0; r < 15; ++r) ob[tid + 256 * r] = acc[r];
}

extern "C" void kernel_launch(void* const* d_in, const int* in_sizes, int n_in,
                              void* d_out, int out_size, void* d_ws, size_t ws_size,
                              hipStream_t stream) {
    const float* x     = (const float*)d_in[0];
    const float* ea    = (const float*)d_in[1];
    const int*   ei    = (const int*)d_in[2];
    const float* We    = (const float*)d_in[3];
    const float* be    = (const float*)d_in[4];
    const float* Wc    = (const float*)d_in[5];
    const float* gamma = (const float*)d_in[6];
    const float* beta  = (const float*)d_in[7];
    const int E = in_sizes[2] / 2;
    const int* src = ei;
    const int* dst = ei + E;

    char* ws = (char*)d_ws;
    size_t off = 0;
    auto alloc = [&](size_t bytes) -> void* {
        void* p = ws + off;
        off += (bytes + 255) & ~(size_t)255;
        return p;
    };
    float*          A      = (float*)alloc((size_t)N_NODES * CH * 4);
    float*          Bm     = (float*)alloc((size_t)N_NODES * CH * 4);
    float*          cbuf   = (float*)alloc((size_t)E * 256 * 4);
    unsigned short* Wfrag  = (unsigned short*)alloc(512 * 256 * 2);
    float*          M      = (float*)alloc(5 * 256 * 4);
    float*          bias0  = (float*)alloc(256 * 4);
    int*            counts = (int*)alloc(N_NODES * 4);
    int*            cursor = (int*)alloc(N_NODES * 4);
    int*            offs   = (int*)alloc((N_NODES + 1) * 4);
    int*            elist  = (int*)alloc((size_t)E * 4);

    hipMemsetAsync(counts, 0, N_NODES * 4, stream);
    hipMemsetAsync(cursor, 0, N_NODES * 4, stream);

    k_prep_wfrag<<<512, 256, 0, stream>>>(Wc, Wfrag);
    k_prep_m<<<1, 256, 0, stream>>>(Wc, We, be, M, bias0);
    k_edge_c<<<E, 256, 0, stream>>>(ea, M, bias0, cbuf);
    k_count<<<(E + 255) / 256, 256, 0, stream>>>(dst, E, counts);
    k_scan<<<1, 512, 0, stream>>>(counts, offs);
    k_fill<<<(E + 255) / 256, 256, 0, stream>>>(dst, E, offs, cursor, elist);
    k_sort<<<2, 192, 0, stream>>>(offs, elist);
    k_node_mfma<<<N_NODES, 256, 0, stream>>>(x, Wfrag, A, Bm);
    k_agg<<<N_NODES, 256, 0, stream>>>(A, Bm, cbuf, src, offs, elist, gamma, beta, (float*)d_out);
}

// Round 3
// 135.938 us; speedup vs baseline: 2.0409x; 1.4217x over previous
//
#include <hip/hip_runtime.h>

#define N_NODES 384
#define CCH 256        // channels
#define HT 60          // height
#define CH (CCH*HT)    // 15360 elements per node slab
#define CH4 (CH/4)     // 3840 4-vectors
#define LN_EPS 1e-5f

typedef __attribute__((ext_vector_type(8))) short bf16x8;
typedef __attribute__((ext_vector_type(4))) float f32x4;

__device__ inline unsigned short f2bf(float f) {
    unsigned int u = __float_as_uint(f);
    unsigned int r = (u + 0x7FFF + ((u >> 16) & 1)) >> 16;   // RNE
    return (unsigned short)r;
}
__device__ inline float bf2f(unsigned short u) {
    return __uint_as_float(((unsigned int)u) << 16);
}

// ---- prep: W_conv -> MFMA A-fragment-linear bf16 buffer.
// Logical A matrix: 512x256, rows 0..255 = W1-W2, rows 256..511 = W2.
__global__ void k_prep_wfrag(const float* __restrict__ Wc, unsigned short* __restrict__ Wfrag) {
    int idx = blockIdx.x * 256 + threadIdx.x;      // 131072 total
    int j = idx & 7, lane = (idx >> 3) & 63, ks = (idx >> 9) & 7, mt = idx >> 12;
    int o = mt * 16 + (lane & 15);
    int c = ks * 32 + (lane >> 4) * 8 + j;
    float v;
    if (o < 256) v = Wc[o * 768 + c] - Wc[o * 768 + 256 + c];   // W1 - W2
    else         v = Wc[(o - 256) * 768 + 256 + c];             // W2
    Wfrag[idx] = f2bf(v);
}

// ---- prep: M[j][o] = sum_k W_edge[j,k]*W3[o,k]; bias0[o] = sum_k b_edge[k]*W3[o,k]
__global__ void k_prep_m(const float* __restrict__ Wc, const float* __restrict__ We,
                         const float* __restrict__ be, float* __restrict__ M,
                         float* __restrict__ bias0) {
    int o = threadIdx.x;
    float m0=0,m1=0,m2=0,m3=0,m4=0,bb=0;
    for (int k = 0; k < 256; ++k) {
        float w3 = Wc[o * 768 + 512 + k];
        m0 += We[0*256+k] * w3;
        m1 += We[1*256+k] * w3;
        m2 += We[2*256+k] * w3;
        m3 += We[3*256+k] * w3;
        m4 += We[4*256+k] * w3;
        bb += be[k] * w3;
    }
    M[0*256+o]=m0; M[1*256+o]=m1; M[2*256+o]=m2; M[3*256+o]=m3; M[4*256+o]=m4;
    bias0[o] = bb;
}

// ---- per-edge coefficient c[e][o] = bias0[o] + sum_j ea[e,j]*M[j,o] ----
__global__ void k_edge_c(const float* __restrict__ ea, const float* __restrict__ M,
                         const float* __restrict__ bias0, float* __restrict__ cbuf) {
    int e = blockIdx.x, o = threadIdx.x;
    float s = bias0[o];
#pragma unroll
    for (int j = 0; j < 5; ++j) s += ea[e * 5 + j] * M[j * 256 + o];
    cbuf[e * 256 + o] = s;
}

// ---- CSR build (dst-indexed), deterministic after per-node sort ----
__global__ void k_count(const int* __restrict__ dst, int E, int* counts) {
    int e = blockIdx.x * 256 + threadIdx.x;
    if (e < E) atomicAdd(&counts[dst[e]], 1);
}
__global__ void k_scan(const int* __restrict__ counts, int* __restrict__ offsets) {
    __shared__ int sc[512];
    int tid = threadIdx.x;
    int v = (tid < N_NODES) ? counts[tid] : 0;
    sc[tid] = v; __syncthreads();
    for (int d = 1; d < 512; d <<= 1) {
        int t = (tid >= d) ? sc[tid - d] : 0;
        __syncthreads();
        sc[tid] += t; __syncthreads();
    }
    if (tid < N_NODES) offsets[tid + 1] = sc[tid];
    if (tid == 0) offsets[0] = 0;
}
__global__ void k_fill(const int* __restrict__ dst, int E, const int* __restrict__ offsets,
                       int* cursor, int* __restrict__ elist) {
    int e = blockIdx.x * 256 + threadIdx.x;
    if (e < E) {
        int d = dst[e];
        int slot = offsets[d] + atomicAdd(&cursor[d], 1);
        elist[slot] = e;
    }
}
__global__ void k_sort(const int* __restrict__ offsets, int* __restrict__ elist) {
    int n = blockIdx.x * blockDim.x + threadIdx.x;
    if (n >= N_NODES) return;
    int lo = offsets[n], hi = offsets[n + 1];
    for (int i = lo + 1; i < hi; ++i) {
        int key = elist[i]; int j = i - 1;
        while (j >= lo && elist[j] > key) { elist[j + 1] = elist[j]; --j; }
        elist[j + 1] = key;
    }
}

// ---- per-node GEMM via MFMA: [A;B](512x60) = Wstacked(512x256) @ x[n](256x60)
// Outputs bf16 slabs Abf/Bbf laid out [n][o][h].
__global__ __launch_bounds__(256) void k_node_mfma(const float* __restrict__ x,
                                                   const unsigned short* __restrict__ Wfrag,
                                                   unsigned short* __restrict__ Abf,
                                                   unsigned short* __restrict__ Bbf) {
    __shared__ unsigned short xT[64 * 256];   // 32 KiB, [h][c] bf16, swizzled
    int n = blockIdx.x, tid = threadIdx.x;

    // zero pad rows h=60..63
    for (int i = tid; i < 4 * 256; i += 256) {
        int h = 60 + (i >> 8), c = i & 255;
        xT[h * 256 + (c ^ ((h & 7) << 3))] = 0;
    }
    const float4* xg = (const float4*)(x + (size_t)n * CH);
    for (int i = tid; i < CH4; i += 256) {
        int c = i / 15;
        int h0 = (i - c * 15) * 4;
        float4 v = xg[i];
        xT[(h0+0) * 256 + (c ^ (((h0+0) & 7) << 3))] = f2bf(v.x);
        xT[(h0+1) * 256 + (c ^ (((h0+1) & 7) << 3))] = f2bf(v.y);
        xT[(h0+2) * 256 + (c ^ (((h0+2) & 7) << 3))] = f2bf(v.z);
        xT[(h0+3) * 256 + (c ^ (((h0+3) & 7) << 3))] = f2bf(v.w);
    }
    __syncthreads();

    int w = tid >> 6, lane = tid & 63;
    int l15 = lane & 15, lg = lane >> 4;

    f32x4 acc[8][4];
#pragma unroll
    for (int mt = 0; mt < 8; ++mt)
#pragma unroll
        for (int nt = 0; nt < 4; ++nt)
            acc[mt][nt] = (f32x4){0.f, 0.f, 0.f, 0.f};

    const unsigned short* wbase = Wfrag + ((size_t)(w * 8) * 8 + 0) * 64 * 8;
    for (int ks = 0; ks < 8; ++ks) {
        bf16x8 bfr[4];
#pragma unroll
        for (int nt = 0; nt < 4; ++nt) {
            int row = nt * 16 + l15;
            int col = ks * 32 + lg * 8;
            int idx = row * 256 + (col ^ ((row & 7) << 3));
            bfr[nt] = *(const bf16x8*)(&xT[idx]);
        }
#pragma unroll
        for (int mt = 0; mt < 8; ++mt) {
            const bf16x8 afr = *(const bf16x8*)(wbase + (((size_t)mt * 8 + ks) * 64 + lane) * 8);
#pragma unroll
            for (int nt = 0; nt < 4; ++nt)
                acc[mt][nt] = __builtin_amdgcn_mfma_f32_16x16x32_bf16(afr, bfr[nt], acc[mt][nt], 0, 0, 0);
        }
    }

    // epilogue: D[o = mtg*16 + 4*lg + r][h = nt*16 + l15] -> bf16
#pragma unroll
    for (int mt = 0; mt < 8; ++mt) {
        int mtg = w * 8 + mt;
        int obase = mtg * 16 + 4 * lg;
        unsigned short* dst0 = (obase < 256)
            ? (Abf + (size_t)n * CH + (size_t)obase * 60)
            : (Bbf + (size_t)n * CH + (size_t)(obase - 256) * 60);
#pragma unroll
        for (int nt = 0; nt < 4; ++nt) {
            int h = nt * 16 + l15;
            if (h < 60) {
#pragma unroll
                for (int r = 0; r < 4; ++r)
                    dst0[r * 60 + h] = f2bf(acc[mt][nt][r]);
            }
        }
    }
}

// ---- per-edge LN stats: mu, rstd over m = A[dst] + B[src] + c_e  (one block/edge)
__global__ __launch_bounds__(256) void k_edge_stats(const unsigned short* __restrict__ Abf,
                                                    const unsigned short* __restrict__ Bbf,
                                                    const float* __restrict__ cbuf,
                                                    const int* __restrict__ srcArr,
                                                    const int* __restrict__ dstArr,
                                                    float2* __restrict__ stats) {
    __shared__ float red[8];
    int e = blockIdx.x, tid = threadIdx.x;
    int lane = tid & 63, wv = tid >> 6;
    int s = srcArr[e], d = dstArr[e];
    const ushort4* Ab = (const ushort4*)(Abf + (size_t)d * CH);
    const ushort4* Bb = (const ushort4*)(Bbf + (size_t)s * CH);
    const float* cc = cbuf + (size_t)e * 256;
    float s1 = 0.f, s2 = 0.f;
    for (int i = tid; i < CH4; i += 256) {     // each ushort4 = 4 h of one channel (60%4==0)
        int c = i / 15;
        float ccv = cc[c];
        ushort4 av = Ab[i];
        ushort4 bv = Bb[i];
#pragma unroll
        for (int j = 0; j < 4; ++j) {
            float a = bf2f(((const unsigned short*)&av)[j]);
            float b = bf2f(((const unsigned short*)&bv)[j]);
            float v = a + b + ccv;
            s1 += v; s2 += v * v;
        }
    }
#pragma unroll
    for (int off2 = 32; off2 >= 1; off2 >>= 1) {
        s1 += __shfl_xor(s1, off2, 64);
        s2 += __shfl_xor(s2, off2, 64);
    }
    if (lane == 0) { red[wv * 2] = s1; red[wv * 2 + 1] = s2; }
    __syncthreads();
    if (tid == 0) {
        float S1 = red[0] + red[2] + red[4] + red[6];
        float S2 = red[1] + red[3] + red[5] + red[7];
        float mu = S1 * (1.0f / (float)CH);
        float var = S2 * (1.0f / (float)CH) - mu * mu;
        stats[e] = make_float2(mu, rsqrtf(var + LN_EPS));
    }
}

// ---- apply + aggregate: block = (node, channel-quarter), barrier-free inner loop
__global__ __launch_bounds__(256) void k_apply(const unsigned short* __restrict__ Abf,
                                               const unsigned short* __restrict__ Bbf,
                                               const float* __restrict__ cbuf,
                                               const float2* __restrict__ stats,
                                               const int* __restrict__ srcArr,
                                               const int* __restrict__ offsets,
                                               const int* __restrict__ elist,
                                               const float* __restrict__ gamma,
                                               const float* __restrict__ beta,
                                               float* __restrict__ out) {
    int n = blockIdx.x >> 2, cg = blockIdx.x & 3;
    int tid = threadIdx.x;
    size_t sbase = (size_t)n * CH + (size_t)cg * 3840;   // slab element offset
    const ushort4* Ab = (const ushort4*)(Abf + sbase);
    const float4*  g4 = (const float4*)(gamma + (size_t)cg * 3840);
    const float4*  b4 = (const float4*)(beta  + (size_t)cg * 3840);

    // per-thread element indices: vec4 index i = tid + 256*r, r=0..3 (r==3 only tid<192)
    float4 af[4], gv[4], bv[4], acc[4];
    int ci[4];
#pragma unroll
    for (int r = 0; r < 4; ++r) {
        acc[r] = make_float4(0.f, 0.f, 0.f, 0.f);
        af[r] = make_float4(0.f, 0.f, 0.f, 0.f);
        gv[r] = make_float4(0.f, 0.f, 0.f, 0.f);
        bv[r] = make_float4(0.f, 0.f, 0.f, 0.f);
        ci[r] = 0;
    }
#pragma unroll
    for (int r = 0; r < 4; ++r) {
        if (r < 3 || tid < 192) {
            int i = tid + 256 * r;
            ci[r] = i / 15;                 // channel within group (0..63)
            ushort4 aw = Ab[i];
            af[r].x = bf2f(aw.x); af[r].y = bf2f(aw.y);
            af[r].z = bf2f(aw.z); af[r].w = bf2f(aw.w);
            gv[r] = g4[i];
            bv[r] = b4[i];
        }
    }

    int lo = offsets[n], hi = offsets[n + 1];
    for (int k = lo; k < hi; ++k) {
        int e = elist[k];
        int s = srcArr[e];
        float2 st = stats[e];
        float mu = st.x, rstd = st.y;
        const ushort4* Bb = (const ushort4*)(Bbf + (size_t)s * CH + (size_t)cg * 3840);
        const float* cc = cbuf + (size_t)e * 256 + cg * 64;
#pragma unroll
        for (int r = 0; r < 4; ++r) {
            if (r < 3 || tid < 192) {
                int i = tid + 256 * r;
                float ccv = cc[ci[r]];
                ushort4 bw = Bb[i];
                float mx = af[r].x + bf2f(bw.x) + ccv;
                float my = af[r].y + bf2f(bw.y) + ccv;
                float mz = af[r].z + bf2f(bw.z) + ccv;
                float mw = af[r].w + bf2f(bw.w) + ccv;
                float vx = (mx - mu) * rstd * gv[r].x + bv[r].x; vx = fmaxf(vx, 0.f);
                float vy = (my - mu) * rstd * gv[r].y + bv[r].y; vy = fmaxf(vy, 0.f);
                float vz = (mz - mu) * rstd * gv[r].z + bv[r].z; vz = fmaxf(vz, 0.f);
                float vw = (mw - mu) * rstd * gv[r].w + bv[r].w; vw = fmaxf(vw, 0.f);
                acc[r].x += vx; acc[r].y += vy; acc[r].z += vz; acc[r].w += vw;
            }
        }
    }
    float4* ob = (float4*)(out + sbase);
#pragma unroll
    for (int r = 0; r < 4; ++r)
        if (r < 3 || tid < 192) ob[tid + 256 * r] = acc[r];
}

extern "C" void kernel_launch(void* const* d_in, const int* in_sizes, int n_in,
                              void* d_out, int out_size, void* d_ws, size_t ws_size,
                              hipStream_t stream) {
    const float* x     = (const float*)d_in[0];
    const float* ea    = (const float*)d_in[1];
    const int*   ei    = (const int*)d_in[2];
    const float* We    = (const float*)d_in[3];
    const float* be    = (const float*)d_in[4];
    const float* Wc    = (const float*)d_in[5];
    const float* gamma = (const float*)d_in[6];
    const float* beta  = (const float*)d_in[7];
    const int E = in_sizes[2] / 2;
    const int* src = ei;
    const int* dst = ei + E;

    char* ws = (char*)d_ws;
    size_t off = 0;
    auto alloc = [&](size_t bytes) -> void* {
        void* p = ws + off;
        off += (bytes + 255) & ~(size_t)255;
        return p;
    };
    unsigned short* Abf    = (unsigned short*)alloc((size_t)N_NODES * CH * 2);
    unsigned short* Bbf    = (unsigned short*)alloc((size_t)N_NODES * CH * 2);
    float*          cbuf   = (float*)alloc((size_t)E * 256 * 4);
    float2*         stats  = (float2*)alloc((size_t)E * 8);
    unsigned short* Wfrag  = (unsigned short*)alloc(512 * 256 * 2);
    float*          M      = (float*)alloc(5 * 256 * 4);
    float*          bias0  = (float*)alloc(256 * 4);
    int*            counts = (int*)alloc(N_NODES * 4);
    int*            cursor = (int*)alloc(N_NODES * 4);
    int*            offs   = (int*)alloc((N_NODES + 1) * 4);
    int*            elist  = (int*)alloc((size_t)E * 4);

    hipMemsetAsync(counts, 0, N_NODES * 4, stream);
    hipMemsetAsync(cursor, 0, N_NODES * 4, stream);

    k_prep_wfrag<<<512, 256, 0, stream>>>(Wc, Wfrag);
    k_prep_m<<<1, 256, 0, stream>>>(Wc, We, be, M, bias0);
    k_edge_c<<<E, 256, 0, stream>>>(ea, M, bias0, cbuf);
    k_count<<<(E + 255) / 256, 256, 0, stream>>>(dst, E, counts);
    k_scan<<<1, 512, 0, stream>>>(counts, offs);
    k_fill<<<(E + 255) / 256, 256, 0, stream>>>(dst, E, offs, cursor, elist);
    k_sort<<<2, 192, 0, stream>>>(offs, elist);
    k_node_mfma<<<N_NODES, 256, 0, stream>>>(x, Wfrag, Abf, Bbf);
    k_edge_stats<<<E, 256, 0, stream>>>(Abf, Bbf, cbuf, src, dst, stats);
    k_apply<<<N_NODES * 4, 256, 0, stream>>>(Abf, Bbf, cbuf, stats, src, offs, elist,
                                             gamma, beta, (float*)d_out);
}